// Round 4
// baseline (1721.633 us; speedup 1.0000x reference)
//
#include <hip/hip_runtime.h>

#define M 256     // rows of S (n_hos*n_types)
#define N 4096    // cols of S (n_structs)
#define NIT 200   // PDHG iterations
#define PIT 30    // power iterations
#define CSRCAP 131072

typedef _Float16 h2 __attribute__((ext_vector_type(2)));

// dummy byte-offsets (4-byte slots): y_s[256], z_s[4096]
#define YDUMMY (256*4)
#define ZDUMMY (4096*4)

static __device__ inline h2 h2pk(float a, float b){
  h2 r; r.x = (_Float16)a; r.y = (_Float16)b; return r;
}

// ---------------- counts ----------------
__global__ void k_colcnt(const float* __restrict__ S, int* __restrict__ col_cnt){
  int j = blockIdx.x*256 + threadIdx.x;
  int c = 0;
  for (int i = 0; i < M; ++i) c += (S[i*N + j] != 0.0f) ? 1 : 0;
  col_cnt[j] = c;
}

__global__ void k_rowcnt(const float* __restrict__ S, int* __restrict__ row_cnt){
  int wid = blockIdx.x*(blockDim.x>>6) + (threadIdx.x>>6);
  int l = threadIdx.x & 63;
  if (wid >= M) return;
  int cnt = 0;
  for (int jc = 0; jc < N/64; ++jc){
    float v = S[wid*N + jc*64 + l];
    unsigned long long mask = __ballot(v != 0.0f);
    cnt += __popcll(mask);
  }
  if (l == 0) row_cnt[wid] = cnt;
}

// ---------------- deterministic rank sort by (cnt, index) ----------------
__global__ void k_sortcol(const int* __restrict__ col_cnt,
                          int* __restrict__ col_perm, int* __restrict__ col_rank){
  __shared__ int cs[N];
  int t0 = threadIdx.x;
  for (int t = 0; t < N/256; ++t) cs[t0 + 256*t] = col_cnt[t0 + 256*t];
  __syncthreads();
  int j = blockIdx.x*256 + t0;
  int cj = cs[j];
  int rank = 0;
  #pragma unroll 4
  for (int jj = 0; jj < N; ++jj){
    int c = cs[jj];
    rank += ((c < cj) || (c == cj && jj < j)) ? 1 : 0;
  }
  col_perm[rank] = j;
  col_rank[j] = rank;
}

__global__ void k_sortrow(const int* __restrict__ row_cnt,
                          int* __restrict__ row_perm, int* __restrict__ row_ptr){
  int i = threadIdx.x;
  int ci = row_cnt[i];
  int rank = 0, pre = 0;
  for (int ii = 0; ii < M; ++ii){
    int c = row_cnt[ii];
    bool less = (c < ci) || (c == ci && ii < i);
    rank += less ? 1 : 0;
    pre  += less ? c : 0;
  }
  row_perm[rank] = i;
  row_ptr[rank]  = pre;
}

// ---------------- CSR fill (4-byte-slot offsets) ----------------
__global__ void k_fillcsr(const float* __restrict__ S, const int* __restrict__ row_perm,
                          const int* __restrict__ row_ptr, unsigned short* __restrict__ csr){
  int rr = blockIdx.x*(blockDim.x>>6) + (threadIdx.x>>6);
  int l = threadIdx.x & 63;
  if (rr >= M) return;
  int i = row_perm[rr];
  int pos = row_ptr[rr];
  for (int jc = 0; jc < N/64; ++jc){
    float v = S[i*N + jc*64 + l];
    unsigned long long mask = __ballot(v != 0.0f);
    if (v != 0.0f){
      int off = __popcll(mask & ((1ull << l) - 1ull));
      int p = pos + off;
      if (p < CSRCAP) csr[p] = (unsigned short)((jc*64 + l)*4);
    }
    pos += __popcll(mask);
  }
}

// ---------------- wave-trip counts + base offsets (TRIP units) ----------
__global__ void k_trips(const int* __restrict__ col_cnt, const int* __restrict__ col_perm,
                        const int* __restrict__ row_cnt, const int* __restrict__ row_perm,
                        int* __restrict__ pT4, int* __restrict__ pB4,
                        int* __restrict__ dT4, int* __restrict__ dB4){
  int tid = threadIdx.x;
  if (tid < 64){
    int k = tid >> 4, w = tid & 15;
    int mx = 0;
    for (int l = 0; l < 64; ++l){
      int s = 64*w + l + 1024*k;
      int c = col_cnt[col_perm[s]];
      mx = max(mx, c);
    }
    pT4[tid] = min((mx + 3) >> 2, 16);
  } else if (tid < 80){
    int w = tid - 64;
    int mx = 0;
    for (int l = 0; l < 64; ++l){
      int t = 64*w + l;
      int r = t & 255, q = t >> 8;
      int len = row_cnt[row_perm[r]];
      int qs = (len*q) >> 2, qe = (len*(q+1)) >> 2;
      mx = max(mx, qe - qs);
    }
    dT4[w] = min((mx + 3) >> 2, 80);
  }
  __syncthreads();
  if (tid == 0){
    int acc = 0;
    for (int i = 0; i < 64; ++i){ pB4[i] = acc; acc += pT4[i]; }
    acc = 0;
    for (int i = 0; i < 16; ++i){ dB4[i] = acc; acc += dT4[i]; }
  }
}

// ---------------- primal stream fill (stagger-sorted, padded) -----------
__global__ void k_fillp(const float* __restrict__ S, const int* __restrict__ col_rank,
                        const int* __restrict__ pT4, const int* __restrict__ pB4,
                        unsigned short* __restrict__ pstream){
  int j = blockIdx.x*256 + threadIdx.x;
  int s = col_rank[j];
  int k = s >> 10, rem = s & 1023, w = rem >> 6, l = rem & 63;
  int kw = k*16 + w;
  int base = pB4[kw];
  int cap = pT4[kw]*4;
  int ls = l & 31;
  unsigned short items[64];
  int n = 0;
  for (int i = 0; i < M && n < cap; ++i)
    if (S[i*N + j] != 0.0f) items[n++] = (unsigned short)i;
  // selection sort by staggered-bank key (deterministic)
  for (int t = 0; t < n; ++t){
    int best = t;
    int bk = ((((int)items[t] & 31) + 32 - ls) & 31)*256 + (int)items[t];
    for (int u = t+1; u < n; ++u){
      int ku = ((((int)items[u] & 31) + 32 - ls) & 31)*256 + (int)items[u];
      if (ku < bk){ bk = ku; best = u; }
    }
    unsigned short tmp = items[t]; items[t] = items[best]; items[best] = tmp;
  }
  int t = 0;
  for (; t < n; ++t)
    pstream[((base + (t>>2))*64 + l)*4 + (t&3)] = (unsigned short)(items[t]*4);
  for (; t < cap; ++t)
    pstream[((base + (t>>2))*64 + l)*4 + (t&3)] = (unsigned short)YDUMMY;
}

// ---------------- dual stream fill (stagger-sorted, padded) -------------
__global__ void k_filld(const unsigned short* __restrict__ csr,
                        const int* __restrict__ row_cnt, const int* __restrict__ row_perm,
                        const int* __restrict__ row_ptr,
                        const int* __restrict__ dT4, const int* __restrict__ dB4,
                        unsigned short* __restrict__ dstream){
  int tid = blockIdx.x*256 + threadIdx.x;   // 1024 total, same mapping as k_main
  int w = tid >> 6, l = tid & 63;
  int r = tid & 255, q = tid >> 8;
  int ls = l & 31;
  int len = row_cnt[row_perm[r]];
  int rb = row_ptr[r];
  int qs = (len*q) >> 2, qe = (len*(q+1)) >> 2;
  int base = dB4[w];
  int cap = dT4[w]*4;
  int qlen = qe - qs; if (qlen > cap) qlen = cap;
  unsigned short items[96];
  int sn = qlen < 96 ? qlen : 96;
  for (int t = 0; t < sn; ++t) items[t] = csr[rb + qs + t];
  for (int t = 0; t < sn; ++t){
    int best = t;
    int bk = (((((int)items[t] >> 2) & 31) + 32 - ls) & 31)*65536 + (int)items[t];
    for (int u = t+1; u < sn; ++u){
      int ku = (((((int)items[u] >> 2) & 31) + 32 - ls) & 31)*65536 + (int)items[u];
      if (ku < bk){ bk = ku; best = u; }
    }
    unsigned short tmp = items[t]; items[t] = items[best]; items[best] = tmp;
  }
  int t = 0;
  for (; t < sn; ++t)
    dstream[((base + (t>>2))*64 + l)*4 + (t&3)] = items[t];
  for (; t < qlen; ++t)
    dstream[((base + (t>>2))*64 + l)*4 + (t&3)] = csr[rb + qs + t];
  for (; t < cap; ++t)
    dstream[((base + (t>>2))*64 + l)*4 + (t&3)] = (unsigned short)ZDUMMY;
}

// ---------------- power iteration (no per-step normalize) ---------------
// v <- (S^T S v)/1024 each step (exact pow2 scale); L = Rayleigh at end.
__global__ __launch_bounds__(1024) void k_power(
    const ushort4* __restrict__ pstream, const ushort4* __restrict__ dstream,
    const int* __restrict__ col_perm, const int* __restrict__ row_perm,
    const int* __restrict__ pT4, const int* __restrict__ pB4,
    const int* __restrict__ dT4, const int* __restrict__ dB4,
    float* __restrict__ tauw)
{
  __shared__ float v_s[N+8];
  __shared__ float u_s[M+8];
  __shared__ float2 red2[1024];
  const int tid = threadIdx.x, w = tid >> 6, l = tid & 63;

  int cj[4], pb[4], pt[4];
  float tl[4];
  #pragma unroll
  for (int k = 0; k < 4; ++k){
    int kw = k*16 + w;
    pb[k] = pB4[kw]; pt[k] = pT4[kw];
    cj[k] = col_perm[tid + 1024*k];
    v_s[cj[k]] = 1.0f;
    tl[k] = 0.0f;
  }
  const int r = tid & 255;
  const int rid = row_perm[r];
  const int db = dB4[w], dt = dT4[w];
  if (tid < 8){ v_s[N+tid] = 0.0f; u_s[M+tid] = 0.0f; }
  __syncthreads();

  const char* vb = (const char*)v_s;
  const char* ub = (const char*)u_s;

  for (int it = 0; it < PIT; ++it){
    // u = S v (quarter-row partials)
    float a = 0.0f;
    for (int c = 0; c < dt; ++c){
      ushort4 ix = dstream[(db + c)*64 + l];
      a += *(const float*)(vb + ix.x) + *(const float*)(vb + ix.y)
         + *(const float*)(vb + ix.z) + *(const float*)(vb + ix.w);
    }
    red2[tid].x = a;
    __syncthreads();
    if (tid < M){
      float f = (red2[tid].x + red2[tid+256].x) + (red2[tid+512].x + red2[tid+768].x);
      u_s[rid] = f;
    }
    __syncthreads();
    // v = (S^T u)/1024
    #pragma unroll
    for (int k = 0; k < 4; ++k){
      float a2 = 0.0f;
      for (int c = 0; c < pt[k]; ++c){
        ushort4 ix = pstream[(pb[k] + c)*64 + l];
        a2 += *(const float*)(ub + ix.x) + *(const float*)(ub + ix.y)
            + *(const float*)(ub + ix.z) + *(const float*)(ub + ix.w);
      }
      tl[k] = a2 * (1.0f/1024.0f);
    }
    __syncthreads();              // everyone done reading u_s / old v_s
    #pragma unroll
    for (int k = 0; k < 4; ++k) v_s[cj[k]] = tl[k];
    __syncthreads();
  }

  // L^2 = ||S v||^2 / ||v||^2
  float pv = 0.0f;
  #pragma unroll
  for (int k = 0; k < 4; ++k) pv += tl[k]*tl[k];
  float a = 0.0f;
  for (int c = 0; c < dt; ++c){
    ushort4 ix = dstream[(db + c)*64 + l];
    a += *(const float*)(vb + ix.x) + *(const float*)(vb + ix.y)
       + *(const float*)(vb + ix.z) + *(const float*)(vb + ix.w);
  }
  red2[tid].x = a;
  __syncthreads();
  float fsq = 0.0f;
  if (tid < M){
    float f = (red2[tid].x + red2[tid+256].x) + (red2[tid+512].x + red2[tid+768].x);
    fsq = f*f;
  }
  __syncthreads();
  red2[tid] = make_float2(pv, fsq);
  __syncthreads();
  for (int sd = 512; sd > 0; sd >>= 1){
    if (tid < sd){
      red2[tid].x += red2[tid+sd].x;
      red2[tid].y += red2[tid+sd].y;
    }
    __syncthreads();
  }
  if (tid == 0) tauw[0] = 0.9f * sqrtf(red2[0].x / red2[0].y);
}

// ---------------- persistent PDHG: one block per 2 batches (fp16 LDS) ---
__global__ __launch_bounds__(1024) void k_main(
    const float* __restrict__ X,
    const ushort4* __restrict__ pstream, const ushort4* __restrict__ dstream,
    const int* __restrict__ col_perm, const int* __restrict__ row_perm,
    const int* __restrict__ pT4, const int* __restrict__ pB4,
    const int* __restrict__ dT4, const int* __restrict__ dB4,
    const float* __restrict__ tauw, float* __restrict__ out)
{
  __shared__ h2 z_s[N+8];
  __shared__ h2 y_s[M+8];
  __shared__ float2 part[1024];
  const int tid = threadIdx.x, w = tid >> 6, l = tid & 63;
  const int b0 = blockIdx.x * 2;
  const float tau = tauw[0];
  const float sigma = tau;

  int cj[4], pb[4], pt[4];
  float2 x[4];
  #pragma unroll
  for (int k = 0; k < 4; ++k){
    int kw = k*16 + w;
    pb[k] = pB4[kw]; pt[k] = pT4[kw];
    cj[k] = col_perm[tid + 1024*k];
    x[k] = make_float2(0.0f, 0.0f);
  }
  const int r = tid & 255;
  const int rid = row_perm[r];
  const int db = dB4[w], dt = dT4[w];
  float2 bi = make_float2(0,0), yv = make_float2(0,0);
  if (tid < M){
    bi.x = X[b0*M + rid];
    bi.y = X[(b0+1)*M + rid];
    y_s[rid] = h2pk(0.0f, 0.0f);
  }
  if (tid >= 256 && tid < 264){ y_s[M + (tid-256)] = h2pk(0.0f,0.0f); }
  if (tid >= 264 && tid < 272){ z_s[N + (tid-264)] = h2pk(0.0f,0.0f); }
  __syncthreads();

  const char* yb = (const char*)y_s;
  const char* zb = (const char*)z_s;

  for (int it = 0; it < NIT; ++it){
    // primal: x+ = max(x + tau*(1 - y S), 0); z = 2 x+ - x
    #pragma unroll
    for (int k = 0; k < 4; ++k){
      float ax = 0.0f, ay = 0.0f;
      for (int c = 0; c < pt[k]; ++c){
        ushort4 ix = pstream[(pb[k] + c)*64 + l];
        h2 a0 = *(const h2*)(yb + ix.x);
        h2 a1 = *(const h2*)(yb + ix.y);
        h2 a2 = *(const h2*)(yb + ix.z);
        h2 a3 = *(const h2*)(yb + ix.w);
        ax += ((float)a0.x + (float)a1.x) + ((float)a2.x + (float)a3.x);
        ay += ((float)a0.y + (float)a1.y) + ((float)a2.y + (float)a3.y);
      }
      float2 xo = x[k];
      float xnx = fmaxf(xo.x + tau*(1.0f - ax), 0.0f);
      float xny = fmaxf(xo.y + tau*(1.0f - ay), 0.0f);
      z_s[cj[k]] = h2pk(2.0f*xnx - xo.x, 2.0f*xny - xo.y);
      x[k] = make_float2(xnx, xny);
    }
    __syncthreads();
    // dual partial sums (quarter rows)
    {
      float ax = 0.0f, ay = 0.0f;
      for (int c = 0; c < dt; ++c){
        ushort4 ix = dstream[(db + c)*64 + l];
        h2 a0 = *(const h2*)(zb + ix.x);
        h2 a1 = *(const h2*)(zb + ix.y);
        h2 a2 = *(const h2*)(zb + ix.z);
        h2 a3 = *(const h2*)(zb + ix.w);
        ax += ((float)a0.x + (float)a1.x) + ((float)a2.x + (float)a3.x);
        ay += ((float)a0.y + (float)a1.y) + ((float)a2.y + (float)a3.y);
      }
      part[tid] = make_float2(ax, ay);
    }
    __syncthreads();
    if (tid < M){
      float2 p0 = part[tid], p1 = part[tid+256], p2 = part[tid+512], p3 = part[tid+768];
      float fx = (p0.x + p1.x) + (p2.x + p3.x);
      float fy = (p0.y + p1.y) + (p2.y + p3.y);
      yv.x = fmaxf(yv.x + sigma*(fx - bi.x), 0.0f);
      yv.y = fmaxf(yv.y + sigma*(fy - bi.y), 0.0f);
      y_s[rid] = h2pk(yv.x, yv.y);
    }
    __syncthreads();
  }

  #pragma unroll
  for (int k = 0; k < 4; ++k){
    out[(size_t)b0*N + cj[k]]     = x[k].x;
    out[(size_t)(b0+1)*N + cj[k]] = x[k].y;
  }
}

// ---------------- launcher ----------------
extern "C" void kernel_launch(void* const* d_in, const int* in_sizes, int n_in,
                              void* d_out, int out_size, void* d_ws, size_t ws_size,
                              hipStream_t stream)
{
  const float* X = (const float*)d_in[0];   // [B, 16, 16] -> b
  const float* S = (const float*)d_in[1];   // [M, N]
  float* out = (float*)d_out;               // [B, N] fp32
  const int B = in_sizes[0] / M;            // 512

  char* p = (char*)d_ws;
  auto alloc = [&](size_t bytes)->char*{
    char* q = p; p += (bytes + 255) & ~size_t(255); return q;
  };
  int* col_cnt  = (int*)alloc(N*sizeof(int));
  int* col_perm = (int*)alloc(N*sizeof(int));
  int* col_rank = (int*)alloc(N*sizeof(int));
  int* row_cnt  = (int*)alloc(M*sizeof(int));
  int* row_perm = (int*)alloc(M*sizeof(int));
  int* row_ptr  = (int*)alloc(M*sizeof(int));
  int* pT4      = (int*)alloc(64*sizeof(int));
  int* pB4      = (int*)alloc(64*sizeof(int));
  int* dT4      = (int*)alloc(16*sizeof(int));
  int* dB4      = (int*)alloc(16*sizeof(int));
  float* tauw   = (float*)alloc(256);
  unsigned short* csr     = (unsigned short*)alloc(CSRCAP*sizeof(unsigned short));
  unsigned short* pstream = (unsigned short*)alloc(65536ull*8);
  unsigned short* dstream = (unsigned short*)alloc(81920ull*8);

  k_colcnt <<<N/256, 256, 0, stream>>>(S, col_cnt);
  k_rowcnt <<<16, 1024, 0, stream>>>(S, row_cnt);
  k_sortcol<<<N/256, 256, 0, stream>>>(col_cnt, col_perm, col_rank);
  k_sortrow<<<1, M, 0, stream>>>(row_cnt, row_perm, row_ptr);
  k_fillcsr<<<16, 1024, 0, stream>>>(S, row_perm, row_ptr, csr);
  k_trips  <<<1, 256, 0, stream>>>(col_cnt, col_perm, row_cnt, row_perm, pT4, pB4, dT4, dB4);
  k_fillp  <<<N/256, 256, 0, stream>>>(S, col_rank, pT4, pB4, pstream);
  k_filld  <<<4, 256, 0, stream>>>(csr, row_cnt, row_perm, row_ptr, dT4, dB4, dstream);
  k_power  <<<1, 1024, 0, stream>>>((const ushort4*)pstream, (const ushort4*)dstream,
                                    col_perm, row_perm, pT4, pB4, dT4, dB4, tauw);
  k_main   <<<B/2, 1024, 0, stream>>>(X, (const ushort4*)pstream, (const ushort4*)dstream,
                                      col_perm, row_perm, pT4, pB4, dT4, dB4, tauw, out);
}

// Round 5
// 1331.681 us; speedup vs baseline: 1.2928x; 1.2928x over previous
//
#include <hip/hip_runtime.h>

#define M 256     // rows of S (n_hos*n_types)
#define N 4096    // cols of S (n_structs)
#define NIT 200   // PDHG iterations
#define PIT 30    // power iterations
#define CSRCAP 131072

// dummy byte-offsets (float2 slots): y_s[256], z_s[4096]
#define YDUMMY (256*8)
#define ZDUMMY (4096*8)

// ---------------- counts ----------------
__global__ void k_colcnt(const float* __restrict__ S, int* __restrict__ col_cnt){
  int j = blockIdx.x*256 + threadIdx.x;
  int c = 0;
  for (int i = 0; i < M; ++i) c += (S[i*N + j] != 0.0f) ? 1 : 0;
  col_cnt[j] = c;
}

__global__ void k_rowcnt(const float* __restrict__ S, int* __restrict__ row_cnt){
  int wid = blockIdx.x*(blockDim.x>>6) + (threadIdx.x>>6);
  int l = threadIdx.x & 63;
  if (wid >= M) return;
  int cnt = 0;
  for (int jc = 0; jc < N/64; ++jc){
    float v = S[wid*N + jc*64 + l];
    unsigned long long mask = __ballot(v != 0.0f);
    cnt += __popcll(mask);
  }
  if (l == 0) row_cnt[wid] = cnt;
}

// ---------------- deterministic rank sort by (cnt, index) ----------------
__global__ void k_sortcol(const int* __restrict__ col_cnt,
                          int* __restrict__ col_perm, int* __restrict__ col_rank){
  __shared__ int cs[N];
  int t0 = threadIdx.x;
  for (int t = 0; t < N/256; ++t) cs[t0 + 256*t] = col_cnt[t0 + 256*t];
  __syncthreads();
  int j = blockIdx.x*256 + t0;
  int cj = cs[j];
  int rank = 0;
  #pragma unroll 4
  for (int jj = 0; jj < N; ++jj){
    int c = cs[jj];
    rank += ((c < cj) || (c == cj && jj < j)) ? 1 : 0;
  }
  col_perm[rank] = j;
  col_rank[j] = rank;
}

__global__ void k_sortrow(const int* __restrict__ row_cnt,
                          int* __restrict__ row_perm, int* __restrict__ row_ptr){
  int i = threadIdx.x;
  int ci = row_cnt[i];
  int rank = 0, pre = 0;
  for (int ii = 0; ii < M; ++ii){
    int c = row_cnt[ii];
    bool less = (c < ci) || (c == ci && ii < i);
    rank += less ? 1 : 0;
    pre  += less ? c : 0;
  }
  row_perm[rank] = i;
  row_ptr[rank]  = pre;
}

// ---------------- CSR fill (float2-slot byte offsets) ----------------
__global__ void k_fillcsr(const float* __restrict__ S, const int* __restrict__ row_perm,
                          const int* __restrict__ row_ptr, unsigned short* __restrict__ csr){
  int rr = blockIdx.x*(blockDim.x>>6) + (threadIdx.x>>6);
  int l = threadIdx.x & 63;
  if (rr >= M) return;
  int i = row_perm[rr];
  int pos = row_ptr[rr];
  for (int jc = 0; jc < N/64; ++jc){
    float v = S[i*N + jc*64 + l];
    unsigned long long mask = __ballot(v != 0.0f);
    if (v != 0.0f){
      int off = __popcll(mask & ((1ull << l) - 1ull));
      int p = pos + off;
      if (p < CSRCAP) csr[p] = (unsigned short)((jc*64 + l)*8);
    }
    pos += __popcll(mask);
  }
}

// ---------------- wave-trip counts + base offsets (TRIP units) ----------
// dual mapping (matches k_main): tid -> r = tid>>2, q = tid&3
__global__ void k_trips(const int* __restrict__ col_cnt, const int* __restrict__ col_perm,
                        const int* __restrict__ row_cnt, const int* __restrict__ row_perm,
                        int* __restrict__ pT4, int* __restrict__ pB4,
                        int* __restrict__ dT4, int* __restrict__ dB4){
  int tid = threadIdx.x;
  if (tid < 64){
    int k = tid >> 4, w = tid & 15;
    int mx = 0;
    for (int l = 0; l < 64; ++l){
      int s = 64*w + l + 1024*k;
      int c = col_cnt[col_perm[s]];
      mx = max(mx, c);
    }
    pT4[tid] = min((mx + 3) >> 2, 16);
  } else if (tid < 80){
    int w = tid - 64;
    int mx = 0;
    for (int l = 0; l < 64; ++l){
      int t = w*64 + l;
      int r = t >> 2, q = t & 3;
      int len = row_cnt[row_perm[r]];
      int qs = (len*q) >> 2, qe = (len*(q+1)) >> 2;
      mx = max(mx, qe - qs);
    }
    dT4[w] = min((mx + 3) >> 2, 80);
  }
  __syncthreads();
  if (tid == 0){
    int acc = 0;
    for (int i = 0; i < 64; ++i){ pB4[i] = acc; acc += pT4[i]; }
    acc = 0;
    for (int i = 0; i < 16; ++i){ dB4[i] = acc; acc += dT4[i]; }
  }
}

// ---------------- primal stream fill (transposed, padded) ----------------
__global__ void k_fillp(const float* __restrict__ S, const int* __restrict__ col_rank,
                        const int* __restrict__ pT4, const int* __restrict__ pB4,
                        unsigned short* __restrict__ pstream){
  int j = blockIdx.x*256 + threadIdx.x;
  int s = col_rank[j];
  int k = s >> 10, rem = s & 1023, w = rem >> 6, l = rem & 63;
  int kw = k*16 + w;
  int base = pB4[kw];
  int cap = pT4[kw]*4;
  int t = 0;
  for (int i = 0; i < M && t < cap; ++i){
    if (S[i*N + j] != 0.0f){
      pstream[((base + (t>>2))*64 + l)*4 + (t&3)] = (unsigned short)(i*8);
      ++t;
    }
  }
  for (; t < cap; ++t)
    pstream[((base + (t>>2))*64 + l)*4 + (t&3)] = (unsigned short)YDUMMY;
}

// ---------------- dual stream fill (transposed, padded) ----------------
__global__ void k_filld(const unsigned short* __restrict__ csr,
                        const int* __restrict__ row_cnt, const int* __restrict__ row_perm,
                        const int* __restrict__ row_ptr,
                        const int* __restrict__ dT4, const int* __restrict__ dB4,
                        unsigned short* __restrict__ dstream){
  int tid = blockIdx.x*256 + threadIdx.x;   // 1024 total, same mapping as k_main
  int w = tid >> 6, l = tid & 63;
  int r = tid >> 2, q = tid & 3;
  int len = row_cnt[row_perm[r]];
  int rb = row_ptr[r];
  int qs = (len*q) >> 2, qe = (len*(q+1)) >> 2;
  int base = dB4[w];
  int cap = dT4[w]*4;
  int qlen = qe - qs; if (qlen > cap) qlen = cap;
  int t = 0;
  for (; t < qlen; ++t)
    dstream[((base + (t>>2))*64 + l)*4 + (t&3)] = csr[rb + qs + t];
  for (; t < cap; ++t)
    dstream[((base + (t>>2))*64 + l)*4 + (t&3)] = (unsigned short)ZDUMMY;
}

// ---------------- power iteration (no per-step normalize) ---------------
// v <- (S^T S v)/1024 each step; L = sqrt(||S v||^2 / ||v||^2) at end.
__global__ __launch_bounds__(1024) void k_power(
    const ushort4* __restrict__ pstream, const ushort4* __restrict__ dstream,
    const int* __restrict__ col_perm, const int* __restrict__ row_perm,
    const int* __restrict__ pT4, const int* __restrict__ pB4,
    const int* __restrict__ dT4, const int* __restrict__ dB4,
    float* __restrict__ tauw)
{
  __shared__ float2 v_s[N+8];
  __shared__ float2 u_s[M+8];
  __shared__ float2 red2[1024];
  const int tid = threadIdx.x, w = tid >> 6, l = tid & 63;

  int cj[4], pb[4], pt[4];
  float tl[4];
  #pragma unroll
  for (int k = 0; k < 4; ++k){
    int kw = k*16 + w;
    pb[k] = pB4[kw]; pt[k] = pT4[kw];
    cj[k] = col_perm[tid + 1024*k];
    v_s[cj[k]] = make_float2(1.0f, 0.0f);
    tl[k] = 0.0f;
  }
  const int r = tid >> 2, q = tid & 3;
  const int rid = row_perm[r];
  const int db = dB4[w], dt = dT4[w];
  if (tid < 8){ v_s[N+tid] = make_float2(0,0); u_s[M+tid] = make_float2(0,0); }
  __syncthreads();

  const char* vb = (const char*)v_s;
  const char* ub = (const char*)u_s;

  for (int it = 0; it < PIT; ++it){
    // phase A: u = S v (quarter-row partials, in-wave reduce)
    float a = 0.0f;
    for (int c = 0; c < dt; ++c){
      ushort4 ix = dstream[(db + c)*64 + l];
      a += ((const float2*)(vb + ix.x))->x + ((const float2*)(vb + ix.y))->x
         + ((const float2*)(vb + ix.z))->x + ((const float2*)(vb + ix.w))->x;
    }
    a += __shfl_xor(a, 1);
    a += __shfl_xor(a, 2);
    if (q == 0) u_s[rid] = make_float2(a, 0.0f);
    __syncthreads();
    // phase B: v = (S^T u)/1024
    #pragma unroll
    for (int k = 0; k < 4; ++k){
      float a2 = 0.0f;
      for (int c = 0; c < pt[k]; ++c){
        ushort4 ix = pstream[(pb[k] + c)*64 + l];
        a2 += ((const float2*)(ub + ix.x))->x + ((const float2*)(ub + ix.y))->x
            + ((const float2*)(ub + ix.z))->x + ((const float2*)(ub + ix.w))->x;
      }
      tl[k] = a2 * (1.0f/1024.0f);
      v_s[cj[k]] = make_float2(tl[k], 0.0f);
    }
    __syncthreads();
  }

  // L^2 = ||S v||^2 / ||v||^2
  float pv = 0.0f;
  #pragma unroll
  for (int k = 0; k < 4; ++k) pv += tl[k]*tl[k];
  float a = 0.0f;
  for (int c = 0; c < dt; ++c){
    ushort4 ix = dstream[(db + c)*64 + l];
    a += ((const float2*)(vb + ix.x))->x + ((const float2*)(vb + ix.y))->x
       + ((const float2*)(vb + ix.z))->x + ((const float2*)(vb + ix.w))->x;
  }
  a += __shfl_xor(a, 1);
  a += __shfl_xor(a, 2);
  float fsq = (q == 0) ? a*a : 0.0f;
  red2[tid] = make_float2(pv, fsq);
  __syncthreads();
  for (int sd = 512; sd > 0; sd >>= 1){
    if (tid < sd){
      red2[tid].x += red2[tid+sd].x;
      red2[tid].y += red2[tid+sd].y;
    }
    __syncthreads();
  }
  if (tid == 0) tauw[0] = 0.9f * sqrtf(red2[0].x / red2[0].y);
}

// ---------------- persistent PDHG: one block per 2 batches --------------
__global__ __launch_bounds__(1024) void k_main(
    const float* __restrict__ X,
    const ushort4* __restrict__ pstream, const ushort4* __restrict__ dstream,
    const int* __restrict__ col_perm, const int* __restrict__ row_perm,
    const int* __restrict__ pT4, const int* __restrict__ pB4,
    const int* __restrict__ dT4, const int* __restrict__ dB4,
    const float* __restrict__ tauw, float* __restrict__ out)
{
  __shared__ float2 z_s[N+8];
  __shared__ float2 y_s[M+8];
  const int tid = threadIdx.x, w = tid >> 6, l = tid & 63;
  const int b0 = blockIdx.x * 2;
  const float tau = tauw[0];
  const float sigma = tau;

  int cj[4], pb[4], pt[4];
  float2 x[4];
  #pragma unroll
  for (int k = 0; k < 4; ++k){
    int kw = k*16 + w;
    pb[k] = pB4[kw]; pt[k] = pT4[kw];
    cj[k] = col_perm[tid + 1024*k];
    x[k] = make_float2(0.0f, 0.0f);
  }
  const int r = tid >> 2, q = tid & 3;
  const int rid = row_perm[r];
  const int db = dB4[w], dt = dT4[w];
  float2 bi = make_float2(0,0), yv = make_float2(0,0);
  if (q == 0){
    bi.x = X[b0*M + rid];
    bi.y = X[(b0+1)*M + rid];
    y_s[rid] = make_float2(0,0);
  }
  if (tid < 8){ y_s[M+tid] = make_float2(0,0); z_s[N+tid] = make_float2(0,0); }
  __syncthreads();

  const char* yb = (const char*)y_s;
  const char* zb = (const char*)z_s;

  for (int it = 0; it < NIT; ++it){
    const bool last = (it == NIT-1);
    // primal: x+ = max(x + tau*(1 - y S), 0); z = 2 x+ - x
    #pragma unroll
    for (int k = 0; k < 4; ++k){
      float ax = 0.0f, ay = 0.0f;
      for (int c = 0; c < pt[k]; ++c){
        ushort4 ix = pstream[(pb[k] + c)*64 + l];
        float2 a0 = *(const float2*)(yb + ix.x);
        float2 a1 = *(const float2*)(yb + ix.y);
        float2 a2 = *(const float2*)(yb + ix.z);
        float2 a3 = *(const float2*)(yb + ix.w);
        ax += (a0.x + a1.x) + (a2.x + a3.x);
        ay += (a0.y + a1.y) + (a2.y + a3.y);
      }
      float2 xo = x[k];
      float xnx = fmaxf(xo.x + tau*(1.0f - ax), 0.0f);
      float xny = fmaxf(xo.y + tau*(1.0f - ay), 0.0f);
      if (!last) z_s[cj[k]] = make_float2(2.0f*xnx - xo.x, 2.0f*xny - xo.y);
      x[k] = make_float2(xnx, xny);
    }
    if (last) break;
    __syncthreads();
    // dual: quarter-row gathers + in-wave reduce across q
    float ax = 0.0f, ay = 0.0f;
    for (int c = 0; c < dt; ++c){
      ushort4 ix = dstream[(db + c)*64 + l];
      float2 a0 = *(const float2*)(zb + ix.x);
      float2 a1 = *(const float2*)(zb + ix.y);
      float2 a2 = *(const float2*)(zb + ix.z);
      float2 a3 = *(const float2*)(zb + ix.w);
      ax += (a0.x + a1.x) + (a2.x + a3.x);
      ay += (a0.y + a1.y) + (a2.y + a3.y);
    }
    ax += __shfl_xor(ax, 1);  ay += __shfl_xor(ay, 1);
    ax += __shfl_xor(ax, 2);  ay += __shfl_xor(ay, 2);
    if (q == 0){
      yv.x = fmaxf(yv.x + sigma*(ax - bi.x), 0.0f);
      yv.y = fmaxf(yv.y + sigma*(ay - bi.y), 0.0f);
      y_s[rid] = yv;
    }
    __syncthreads();
  }

  #pragma unroll
  for (int k = 0; k < 4; ++k){
    out[(size_t)b0*N + cj[k]]     = x[k].x;
    out[(size_t)(b0+1)*N + cj[k]] = x[k].y;
  }
}

// ---------------- launcher ----------------
extern "C" void kernel_launch(void* const* d_in, const int* in_sizes, int n_in,
                              void* d_out, int out_size, void* d_ws, size_t ws_size,
                              hipStream_t stream)
{
  const float* X = (const float*)d_in[0];   // [B, 16, 16] -> b
  const float* S = (const float*)d_in[1];   // [M, N]
  float* out = (float*)d_out;               // [B, N] fp32
  const int B = in_sizes[0] / M;            // 512

  char* p = (char*)d_ws;
  auto alloc = [&](size_t bytes)->char*{
    char* q = p; p += (bytes + 255) & ~size_t(255); return q;
  };
  int* col_cnt  = (int*)alloc(N*sizeof(int));
  int* col_perm = (int*)alloc(N*sizeof(int));
  int* col_rank = (int*)alloc(N*sizeof(int));
  int* row_cnt  = (int*)alloc(M*sizeof(int));
  int* row_perm = (int*)alloc(M*sizeof(int));
  int* row_ptr  = (int*)alloc(M*sizeof(int));
  int* pT4      = (int*)alloc(64*sizeof(int));
  int* pB4      = (int*)alloc(64*sizeof(int));
  int* dT4      = (int*)alloc(16*sizeof(int));
  int* dB4      = (int*)alloc(16*sizeof(int));
  float* tauw   = (float*)alloc(256);
  unsigned short* csr     = (unsigned short*)alloc(CSRCAP*sizeof(unsigned short));
  unsigned short* pstream = (unsigned short*)alloc(65536ull*8);
  unsigned short* dstream = (unsigned short*)alloc(81920ull*8);

  k_colcnt <<<N/256, 256, 0, stream>>>(S, col_cnt);
  k_rowcnt <<<16, 1024, 0, stream>>>(S, row_cnt);
  k_sortcol<<<N/256, 256, 0, stream>>>(col_cnt, col_perm, col_rank);
  k_sortrow<<<1, M, 0, stream>>>(row_cnt, row_perm, row_ptr);
  k_fillcsr<<<16, 1024, 0, stream>>>(S, row_perm, row_ptr, csr);
  k_trips  <<<1, 256, 0, stream>>>(col_cnt, col_perm, row_cnt, row_perm, pT4, pB4, dT4, dB4);
  k_fillp  <<<N/256, 256, 0, stream>>>(S, col_rank, pT4, pB4, pstream);
  k_filld  <<<4, 256, 0, stream>>>(csr, row_cnt, row_perm, row_ptr, dT4, dB4, dstream);
  k_power  <<<1, 1024, 0, stream>>>((const ushort4*)pstream, (const ushort4*)dstream,
                                    col_perm, row_perm, pT4, pB4, dT4, dB4, tauw);
  k_main   <<<B/2, 1024, 0, stream>>>(X, (const ushort4*)pstream, (const ushort4*)dstream,
                                      col_perm, row_perm, pT4, pB4, dT4, dB4, tauw, out);
}